// Round 1
// baseline (882.393 us; speedup 1.0000x reference)
//
#include <hip/hip_runtime.h>
#include <hip/hip_bf16.h>

// Problem constants
#define NH    12      // heads
#define HD    64      // head dim
#define NT    576     // tokens (queries)
#define CC    768     // channels
#define M_TOT 13914   // total KV tokens per head (90 special + 72*192 cache)
#define MP    13952   // M padded to multiple of 64
#define NEW0  13338   // where the 576 new k/v tokens land in Kf/Vf

__device__ __forceinline__ float u2f(unsigned int u) {
  union { unsigned int u; float f; } x; x.u = u; return x.f;
}

// ---------------------------------------------------------------------------
// GEMM: C[M,N] = A[M,K=768] @ W[N,K=768]^T + bias
// BM=32, BN=64, BK=32, 256 threads, 2x4 microtile.
// MODE 0: qkv projection, scatter q->Q (prescaled 1/8), k/v -> Kf/Vf tail (bf16)
// MODE 1: output projection, write to out_f[m*768+c]
// ---------------------------------------------------------------------------
template <int MODE>
__global__ __launch_bounds__(256) void gemm_kernel(
    const float* __restrict__ A, const float* __restrict__ W,
    const float* __restrict__ bias, float* __restrict__ out_f,
    __hip_bfloat16* __restrict__ Kf, __hip_bfloat16* __restrict__ Vf) {
  __shared__ float xs[32][36];   // A tile, row stride 36 floats (144B, 16B-aligned)
  __shared__ float wsT[32][68];  // W tile transposed [k][n], stride 68 (272B)

  const int tid = threadIdx.x;
  const int tx = tid & 15;       // 0..15 -> 4 output cols
  const int ty = tid >> 4;       // 0..15 -> 2 output rows
  const int bm = blockIdx.y * 32;
  const int bn = blockIdx.x * 64;

  float acc[2][4] = {{0.f, 0.f, 0.f, 0.f}, {0.f, 0.f, 0.f, 0.f}};

  for (int k0 = 0; k0 < CC; k0 += 32) {
    // stage A tile: 32 rows x 32 cols = 256 float4, one per thread
    {
      const int r = tid >> 3, kq = (tid & 7) << 2;
      float4 v = *(const float4*)(A + (size_t)(bm + r) * CC + k0 + kq);
      *(float4*)&xs[r][kq] = v;
    }
    // stage W tile transposed: 64 rows x 32 cols = 512 float4, two per thread
#pragma unroll
    for (int e0 = 0; e0 < 2; ++e0) {
      const int e = tid + e0 * 256;
      const int r = e >> 3, kq = (e & 7) << 2;
      float4 v = *(const float4*)(W + (size_t)(bn + r) * CC + k0 + kq);
      wsT[kq + 0][r] = v.x;
      wsT[kq + 1][r] = v.y;
      wsT[kq + 2][r] = v.z;
      wsT[kq + 3][r] = v.w;
    }
    __syncthreads();
#pragma unroll
    for (int kk = 0; kk < 32; ++kk) {
      const float a0 = xs[ty * 2 + 0][kk];
      const float a1 = xs[ty * 2 + 1][kk];
      const float4 b = *(const float4*)&wsT[kk][tx * 4];
      acc[0][0] = fmaf(a0, b.x, acc[0][0]);
      acc[0][1] = fmaf(a0, b.y, acc[0][1]);
      acc[0][2] = fmaf(a0, b.z, acc[0][2]);
      acc[0][3] = fmaf(a0, b.w, acc[0][3]);
      acc[1][0] = fmaf(a1, b.x, acc[1][0]);
      acc[1][1] = fmaf(a1, b.y, acc[1][1]);
      acc[1][2] = fmaf(a1, b.z, acc[1][2]);
      acc[1][3] = fmaf(a1, b.w, acc[1][3]);
    }
    __syncthreads();
  }

#pragma unroll
  for (int i = 0; i < 2; ++i) {
    const int m = bm + ty * 2 + i;
#pragma unroll
    for (int j = 0; j < 4; ++j) {
      const int c = bn + tx * 4 + j;
      const float v = acc[i][j] + bias[c];
      if (MODE == 1) {
        out_f[(size_t)m * CC + c] = v;
      } else {
        const int which = c / CC;        // 0=q 1=k 2=v
        const int rem = c - which * CC;
        const int hh = rem >> 6;
        const int dd = rem & 63;
        if (which == 0) {
          // bake in softmax scale 1/sqrt(64)
          out_f[((size_t)hh * NT + m) * HD + dd] = v * 0.125f;
        } else {
          const __hip_bfloat16 bv = __float2bfloat16(v);
          const size_t off = ((size_t)hh * MP + NEW0 + m) * HD + dd;
          if (which == 1) Kf[off] = bv;
          else            Vf[off] = bv;
        }
      }
    }
  }
}

// ---------------------------------------------------------------------------
// Gather: fill Kf/Vf[h][m] for m in [0,13338) from cache/special, zero pad.
// Token map (per head):
//   [0,72)        k_special (12 frames x 6)
//   [72,90)       cache frames 8..10, tokens 0..5 (evicted specials)
//   [90,1626)     cache frames 0..7 (contiguous)
//   [1626,13338)  cache frames 11..71 (contiguous)
//   [13338,13914) new k/v, written by qkv gemm (skip)
//   [13914,13952) pad -> zero
// One thread per (h, m, d-quad).
// ---------------------------------------------------------------------------
__global__ __launch_bounds__(256) void gather_kv(
    const float* __restrict__ kc, const float* __restrict__ vc,
    const float* __restrict__ ksp, const float* __restrict__ vsp,
    __hip_bfloat16* __restrict__ Kf, __hip_bfloat16* __restrict__ Vf) {
  const int idx = blockIdx.x * 256 + threadIdx.x;
  const int per_h = MP * 16;
  if (idx >= NH * per_h) return;
  const int h = idx / per_h;
  const int r = idx - h * per_h;
  const int m = r >> 4;
  const int dq = (r & 15) << 2;
  if (m >= NEW0 && m < M_TOT) return;  // new tokens come from qkv gemm

  const size_t dsto = ((size_t)h * MP + m) * HD + dq;
  __hip_bfloat162* kdst = (__hip_bfloat162*)(Kf + dsto);
  __hip_bfloat162* vdst = (__hip_bfloat162*)(Vf + dsto);

  if (m >= M_TOT) {  // pad
    __hip_bfloat162 z;
    z.x = __float2bfloat16(0.f);
    z.y = __float2bfloat16(0.f);
    kdst[0] = z; kdst[1] = z;
    vdst[0] = z; vdst[1] = z;
    return;
  }

  const float* ksrc;
  const float* vsrc;
  size_t soff;
  if (m < 72) {
    soff = ((size_t)h * 72 + m) * HD + dq;
    ksrc = ksp; vsrc = vsp;
  } else {
    ksrc = kc; vsrc = vc;
    if (m < 90) {
      const int j = m - 72;
      soff = (((size_t)h * 72 + 8 + j / 6) * 192 + (j % 6)) * HD + dq;
    } else if (m < 1626) {
      const int j = m - 90;
      soff = ((size_t)h * 13824 + j) * HD + dq;
    } else {
      const int j = m - 1626;
      soff = ((size_t)h * 13824 + 2112 + j) * HD + dq;
    }
  }
  const float4 kvv = *(const float4*)(ksrc + soff);
  const float4 vvv = *(const float4*)(vsrc + soff);
  __hip_bfloat162 a, b;
  a.x = __float2bfloat16(kvv.x); a.y = __float2bfloat16(kvv.y);
  b.x = __float2bfloat16(kvv.z); b.y = __float2bfloat16(kvv.w);
  kdst[0] = a; kdst[1] = b;
  a.x = __float2bfloat16(vvv.x); a.y = __float2bfloat16(vvv.y);
  b.x = __float2bfloat16(vvv.z); b.y = __float2bfloat16(vvv.w);
  vdst[0] = a; vdst[1] = b;
}

// ---------------------------------------------------------------------------
// Attention: per block = (16 queries, 1 head). Flash-style over 218 tiles of
// 64 tokens. fp32 VALU math; K/V staged bf16->fp32 into padded LDS (stride 68
// floats -> only free 2-way bank dups on b128 reads).
// Thread t: q = t>>4, i = t&15; computes scores for tokens {i,i+16,i+32,i+48}
// and owns output dims [4i,4i+4) of query q.
// ---------------------------------------------------------------------------
__global__ __launch_bounds__(256) void attn_kernel(
    const float* __restrict__ Q, const __hip_bfloat16* __restrict__ Kf,
    const __hip_bfloat16* __restrict__ Vf, float* __restrict__ O) {
  __shared__ float qs[16][68];
  __shared__ float ks[64][68];
  __shared__ float vs[64][68];
  __shared__ float ps[16][68];

  const int tid = threadIdx.x;
  const int h = blockIdx.y;
  const int n0 = blockIdx.x * 16;
  const int q = tid >> 4;
  const int i = tid & 15;
  const int d4 = i << 2;

  // load Q tile (scale already baked in)
  {
    const int qq = tid >> 4, dq = (tid & 15) << 2;
    float4 v = *(const float4*)(Q + ((size_t)h * NT + n0 + qq) * HD + dq);
    *(float4*)&qs[qq][dq] = v;
  }
  __syncthreads();

  // hoist own q row to registers (fully unrolled -> static indexing)
  float4 qv[16];
#pragma unroll
  for (int dq4 = 0; dq4 < 16; ++dq4) qv[dq4] = *(const float4*)&qs[q][dq4 * 4];

  float m_run = -1e30f;
  float l_run = 0.f;
  float o0 = 0.f, o1 = 0.f, o2 = 0.f, o3 = 0.f;

  const __hip_bfloat16* Kh = Kf + (size_t)h * MP * HD;
  const __hip_bfloat16* Vh = Vf + (size_t)h * MP * HD;

  for (int t0 = 0; t0 < MP; t0 += 64) {
    // stage K,V tile: 64 rows x 64 bf16 each; uint4 = 8 bf16; 2 chunks/thread
#pragma unroll
    for (int e0 = 0; e0 < 2; ++e0) {
      const int e = tid + e0 * 256;
      const int rr = e >> 3, c8 = (e & 7) << 3;
      const uint4 kp = *(const uint4*)(Kh + (size_t)(t0 + rr) * HD + c8);
      const uint4 vp = *(const uint4*)(Vh + (size_t)(t0 + rr) * HD + c8);
      float* kd = &ks[rr][c8];
      *(float4*)(kd + 0) = make_float4(u2f(kp.x << 16), u2f(kp.x & 0xffff0000u),
                                       u2f(kp.y << 16), u2f(kp.y & 0xffff0000u));
      *(float4*)(kd + 4) = make_float4(u2f(kp.z << 16), u2f(kp.z & 0xffff0000u),
                                       u2f(kp.w << 16), u2f(kp.w & 0xffff0000u));
      float* vd = &vs[rr][c8];
      *(float4*)(vd + 0) = make_float4(u2f(vp.x << 16), u2f(vp.x & 0xffff0000u),
                                       u2f(vp.y << 16), u2f(vp.y & 0xffff0000u));
      *(float4*)(vd + 4) = make_float4(u2f(vp.z << 16), u2f(vp.z & 0xffff0000u),
                                       u2f(vp.w << 16), u2f(vp.w & 0xffff0000u));
    }
    __syncthreads();

    // scores for this thread's 4 tokens
    float s[4];
#pragma unroll
    for (int c = 0; c < 4; ++c) {
      const int tt = i + (c << 4);
      float acc = 0.f;
#pragma unroll
      for (int dq4 = 0; dq4 < 16; ++dq4) {
        const float4 kv = *(const float4*)&ks[tt][dq4 * 4];
        const float4 qq = qv[dq4];
        acc = fmaf(qq.x, kv.x, acc);
        acc = fmaf(qq.y, kv.y, acc);
        acc = fmaf(qq.z, kv.z, acc);
        acc = fmaf(qq.w, kv.w, acc);
      }
      if (t0 + tt >= M_TOT) acc = -1e30f;  // mask pad
      s[c] = acc;
    }

    // tile max across 4 local + 16 lanes of this q-group
    float mt = fmaxf(fmaxf(s[0], s[1]), fmaxf(s[2], s[3]));
#pragma unroll
    for (int off = 8; off >= 1; off >>= 1) mt = fmaxf(mt, __shfl_xor(mt, off, 16));
    const float m_new = fmaxf(m_run, mt);
    const float corr = __expf(m_run - m_new);

    float psum = 0.f;
#pragma unroll
    for (int c = 0; c < 4; ++c) {
      const float p = __expf(s[c] - m_new);
      ps[q][i + (c << 4)] = p;
      psum += p;
    }
#pragma unroll
    for (int off = 8; off >= 1; off >>= 1) psum += __shfl_xor(psum, off, 16);

    l_run = l_run * corr + psum;
    m_run = m_new;
    o0 *= corr; o1 *= corr; o2 *= corr; o3 *= corr;

    // PV: all 64 tokens of the tile (p rows written/read by the same wave)
#pragma unroll 4
    for (int t = 0; t < 64; ++t) {
      const float p = ps[q][t];
      const float4 v = *(const float4*)&vs[t][d4];
      o0 = fmaf(p, v.x, o0);
      o1 = fmaf(p, v.y, o1);
      o2 = fmaf(p, v.z, o2);
      o3 = fmaf(p, v.w, o3);
    }
    __syncthreads();
  }

  const float rl = 1.f / l_run;
  float4 out;
  out.x = o0 * rl; out.y = o1 * rl; out.z = o2 * rl; out.w = o3 * rl;
  *(float4*)(O + (size_t)(n0 + q) * CC + h * HD + d4) = out;
}

// ---------------------------------------------------------------------------
extern "C" void kernel_launch(void* const* d_in, const int* in_sizes, int n_in,
                              void* d_out, int out_size, void* d_ws,
                              size_t ws_size, hipStream_t stream) {
  const float* x        = (const float*)d_in[0];
  const float* qkv_w    = (const float*)d_in[1];
  const float* qkv_b    = (const float*)d_in[2];
  const float* proj_w   = (const float*)d_in[3];
  const float* proj_b   = (const float*)d_in[4];
  const float* k_cache  = (const float*)d_in[5];
  const float* v_cache  = (const float*)d_in[6];
  const float* k_specl  = (const float*)d_in[7];
  const float* v_specl  = (const float*)d_in[8];
  float* out = (float*)d_out;

  // workspace layout (needs ~46.4 MB)
  char* ws = (char*)d_ws;
  const size_t qbytes = (size_t)NH * NT * HD * 4;     // 1,769,472
  const size_t kvbytes = (size_t)NH * MP * HD * 2;    // 21,430,272
  float* Qw = (float*)ws;
  float* Ow = (float*)(ws + qbytes);
  __hip_bfloat16* Kf = (__hip_bfloat16*)(ws + 2 * qbytes);
  __hip_bfloat16* Vf = (__hip_bfloat16*)(ws + 2 * qbytes + kvbytes);

  // 1) QKV projection: (576 x 2304 x 768)
  gemm_kernel<0><<<dim3(36, 18), 256, 0, stream>>>(x, qkv_w, qkv_b, Qw, Kf, Vf);
  // 2) gather cache/special into Kf/Vf
  {
    const int total4 = NH * MP * 16;
    gather_kv<<<dim3((total4 + 255) / 256), 256, 0, stream>>>(
        k_cache, v_cache, k_specl, v_specl, Kf, Vf);
  }
  // 3) attention
  attn_kernel<<<dim3(NT / 16, NH), 256, 0, stream>>>(Qw, Kf, Vf, Ow);
  // 4) output projection: (576 x 768 x 768)
  gemm_kernel<1><<<dim3(12, 18), 256, 0, stream>>>(Ow, proj_w, proj_b, out,
                                                   nullptr, nullptr);
}

// Round 2
// 220.754 us; speedup vs baseline: 3.9972x; 3.9972x over previous
//
#include <hip/hip_runtime.h>
#include <hip/hip_bf16.h>

// Problem constants
#define NH    12      // heads
#define HD    64      // head dim
#define NT    576     // tokens (queries)
#define CC    768     // channels
#define M_TOT 13914   // total KV tokens per head (90 special + 72*192 cache)
#define MP    13952   // M padded to multiple of 64
#define NTIL  218     // MP / 64
#define NEW0  13338   // where the 576 new k/v tokens land in Kf/Vt

typedef short bf16x8 __attribute__((ext_vector_type(8)));
typedef float f32x4 __attribute__((ext_vector_type(4)));

// ---------------------------------------------------------------------------
// GEMM: C[M,N] = A[M,K=768] @ W[N,K=768]^T + bias
// MODE 0: qkv projection -> Qb (bf16, scaled 1/8), Kf[h][m][d] bf16,
//         Vt[h][d][m] bf16 (transposed)
// MODE 1: output projection, write fp32 out[m*768+c]
// ---------------------------------------------------------------------------
template <int MODE>
__global__ __launch_bounds__(256) void gemm_kernel(
    const float* __restrict__ A, const float* __restrict__ W,
    const float* __restrict__ bias, float* __restrict__ out_f,
    __hip_bfloat16* __restrict__ Qb, __hip_bfloat16* __restrict__ Kf,
    __hip_bfloat16* __restrict__ Vt) {
  __shared__ float xs[32][36];
  __shared__ float wsT[32][68];

  const int tid = threadIdx.x;
  const int tx = tid & 15;
  const int ty = tid >> 4;
  const int bm = blockIdx.y * 32;
  const int bn = blockIdx.x * 64;

  float acc[2][4] = {{0.f, 0.f, 0.f, 0.f}, {0.f, 0.f, 0.f, 0.f}};

  for (int k0 = 0; k0 < CC; k0 += 32) {
    {
      const int r = tid >> 3, kq = (tid & 7) << 2;
      float4 v = *(const float4*)(A + (size_t)(bm + r) * CC + k0 + kq);
      *(float4*)&xs[r][kq] = v;
    }
#pragma unroll
    for (int e0 = 0; e0 < 2; ++e0) {
      const int e = tid + e0 * 256;
      const int r = e >> 3, kq = (e & 7) << 2;
      float4 v = *(const float4*)(W + (size_t)(bn + r) * CC + k0 + kq);
      wsT[kq + 0][r] = v.x;
      wsT[kq + 1][r] = v.y;
      wsT[kq + 2][r] = v.z;
      wsT[kq + 3][r] = v.w;
    }
    __syncthreads();
#pragma unroll
    for (int kk = 0; kk < 32; ++kk) {
      const float a0 = xs[ty * 2 + 0][kk];
      const float a1 = xs[ty * 2 + 1][kk];
      const float4 b = *(const float4*)&wsT[kk][tx * 4];
      acc[0][0] = fmaf(a0, b.x, acc[0][0]);
      acc[0][1] = fmaf(a0, b.y, acc[0][1]);
      acc[0][2] = fmaf(a0, b.z, acc[0][2]);
      acc[0][3] = fmaf(a0, b.w, acc[0][3]);
      acc[1][0] = fmaf(a1, b.x, acc[1][0]);
      acc[1][1] = fmaf(a1, b.y, acc[1][1]);
      acc[1][2] = fmaf(a1, b.z, acc[1][2]);
      acc[1][3] = fmaf(a1, b.w, acc[1][3]);
    }
    __syncthreads();
  }

#pragma unroll
  for (int i = 0; i < 2; ++i) {
    const int m = bm + ty * 2 + i;
#pragma unroll
    for (int j = 0; j < 4; ++j) {
      const int c = bn + tx * 4 + j;
      const float v = acc[i][j] + bias[c];
      if (MODE == 1) {
        out_f[(size_t)m * CC + c] = v;
      } else {
        const int which = c / CC;  // 0=q 1=k 2=v
        const int rem = c - which * CC;
        const int hh = rem >> 6;
        const int dd = rem & 63;
        if (which == 0) {
          Qb[((size_t)hh * NT + m) * HD + dd] = __float2bfloat16(v * 0.125f);
        } else if (which == 1) {
          Kf[((size_t)hh * MP + NEW0 + m) * HD + dd] = __float2bfloat16(v);
        } else {
          Vt[((size_t)hh * HD + dd) * MP + NEW0 + m] = __float2bfloat16(v);
        }
      }
    }
  }
}

// ---------------------------------------------------------------------------
// Token map per head (verified in round 1):
//   [0,72)        special (12 frames x 6)
//   [72,90)       cache frames 8..10, tokens 0..5
//   [90,1626)     cache frames 0..7
//   [1626,13338)  cache frames 11..71
//   [13338,13914) new k/v (from qkv gemm)
// ---------------------------------------------------------------------------
__device__ __forceinline__ const float* kv_src_row(
    const float* __restrict__ cache, const float* __restrict__ special,
    int h, int m) {
  if (m < 72) return special + ((size_t)h * 72 + m) * HD;
  if (m < 90) {
    const int j = m - 72;
    return cache + (((size_t)h * 72 + 8 + j / 6) * 192 + (j % 6)) * HD;
  }
  if (m < 1626) return cache + ((size_t)h * 13824 + (m - 90)) * HD;
  return cache + ((size_t)h * 13824 + 2112 + (m - 1626)) * HD;
}

__global__ __launch_bounds__(256) void gather_k(
    const float* __restrict__ kc, const float* __restrict__ ksp,
    __hip_bfloat16* __restrict__ Kf) {
  const int idx = blockIdx.x * 256 + threadIdx.x;
  const int per_h = NEW0 * 16;
  if (idx >= NH * per_h) return;
  const int h = idx / per_h;
  const int r = idx - h * per_h;
  const int m = r >> 4;
  const int dq = (r & 15) << 2;
  const float* src = kv_src_row(kc, ksp, h, m) + dq;
  const float4 v = *(const float4*)src;
  __hip_bfloat162* dst = (__hip_bfloat162*)(Kf + ((size_t)h * MP + m) * HD + dq);
  __hip_bfloat162 a, b;
  a.x = __float2bfloat16(v.x); a.y = __float2bfloat16(v.y);
  b.x = __float2bfloat16(v.z); b.y = __float2bfloat16(v.w);
  dst[0] = a; dst[1] = b;
}

// V transposed gather: Vt[h][d][m]. Thread = token; loop d; writes coalesced.
__global__ __launch_bounds__(256) void gather_vt(
    const float* __restrict__ vc, const float* __restrict__ vsp,
    __hip_bfloat16* __restrict__ Vt) {
  const int h = blockIdx.y;
  const int m = blockIdx.x * 256 + threadIdx.x;
  if (m >= NEW0) return;
  const float* row = kv_src_row(vc, vsp, h, m);
  __hip_bfloat16* dst = Vt + (size_t)h * HD * MP + m;
#pragma unroll 8
  for (int d = 0; d < HD; ++d)
    dst[(size_t)d * MP] = __float2bfloat16(row[d]);
}

// ---------------------------------------------------------------------------
// MFMA flash attention partial.
// Grid: 432 blocks = 9 qtiles x 12 heads x 4 token stripes, XCD-swizzled.
// Block: 4 waves; wave w owns 16 queries. 64-token KV tiles staged in LDS.
// mfma_f32_16x16x32_bf16 layouts:
//   A frag: lane l elem j = A[l&15][8*(l>>4)+j]
//   B frag: lane l elem j = B[8*(l>>4)+j][l&15]
//   C/D:    lane l reg r  = D[4*(l>>4)+r][l&15]
// ---------------------------------------------------------------------------
__global__ __launch_bounds__(256) void attn_partial(
    const __hip_bfloat16* __restrict__ Qb, const __hip_bfloat16* __restrict__ Kf,
    const __hip_bfloat16* __restrict__ Vt, float* __restrict__ Opart,
    float2* __restrict__ mlpart) {
  __shared__ __align__(16) __hip_bfloat16 ks[64][72];   // [token][d]
  __shared__ __align__(16) __hip_bfloat16 vts[64][72];  // [d][token]
  __shared__ __align__(16) __hip_bfloat16 pl[4][16][72];  // per-wave P [q][t]

  const int tid = threadIdx.x;
  const int w = tid >> 6;
  const int l = tid & 63;
  const int l15 = l & 15;
  const int lg = l >> 4;

  // XCD swizzle: block i -> work (i%8)*54 + i/8; work -> (h, qtile, stripe)
  const int i = blockIdx.x;
  const int work = (i & 7) * 54 + (i >> 3);
  const int h = work / 36;
  const int rem = work - h * 36;
  const int qt = rem >> 2;
  const int s = rem & 3;

  const int q0 = qt * 64 + w * 16;  // wave's first query row

  // Q A-fragments (2 halves of D=64), read once from global
  bf16x8 qf[2];
  {
    const __hip_bfloat16* qp = Qb + ((size_t)h * NT + q0 + l15) * HD + 8 * lg;
    qf[0] = *(const bf16x8*)qp;
    qf[1] = *(const bf16x8*)(qp + 32);
  }

  f32x4 acc_o[4];  // d-tile dt: D[q=4*lg+r][d=16*dt+l15]
#pragma unroll
  for (int dt = 0; dt < 4; ++dt) acc_o[dt] = (f32x4){0.f, 0.f, 0.f, 0.f};
  float m_run[4], l_run[4];
#pragma unroll
  for (int r = 0; r < 4; ++r) { m_run[r] = -1e30f; l_run[r] = 0.f; }

  const __hip_bfloat16* Kh = Kf + (size_t)h * MP * HD;
  const __hip_bfloat16* Vth = Vt + (size_t)h * HD * MP;

  for (int t = s; t < NTIL; t += 4) {
    const int m0 = t * 64;
    // stage K [64 tok][64 d] and Vt [64 d][64 tok]; 2 x uint4 per thread each
#pragma unroll
    for (int e0 = 0; e0 < 2; ++e0) {
      const int c = tid + e0 * 256;
      const int row = c >> 3, c8 = (c & 7) * 8;
      *(uint4*)&ks[row][c8] = *(const uint4*)(Kh + (size_t)(m0 + row) * HD + c8);
      *(uint4*)&vts[row][c8] = *(const uint4*)(Vth + (size_t)row * MP + m0 + c8);
    }
    __syncthreads();

    // QK^T: S[q][t], 4 column tiles of 16 tokens
    f32x4 sc[4];
#pragma unroll
    for (int c = 0; c < 4; ++c) {
      const bf16x8 k0 = *(const bf16x8*)&ks[c * 16 + l15][8 * lg];
      const bf16x8 k1 = *(const bf16x8*)&ks[c * 16 + l15][32 + 8 * lg];
      f32x4 z = (f32x4){0.f, 0.f, 0.f, 0.f};
      z = __builtin_amdgcn_mfma_f32_16x16x32_bf16(qf[0], k0, z, 0, 0, 0);
      sc[c] = __builtin_amdgcn_mfma_f32_16x16x32_bf16(qf[1], k1, z, 0, 0, 0);
    }

    // mask pad tokens (only last tile of stripe 1 has any)
    if (m0 + 64 > M_TOT) {
#pragma unroll
      for (int c = 0; c < 4; ++c)
        if (m0 + c * 16 + l15 >= M_TOT)
          sc[c] = (f32x4){-1e30f, -1e30f, -1e30f, -1e30f};
    }

    // online softmax; lane holds sc[c][r] = S[q0+4*lg+r][m0+16*c+l15]
    float corr[4], psum[4];
#pragma unroll
    for (int r = 0; r < 4; ++r) {
      float v = fmaxf(fmaxf(sc[0][r], sc[1][r]), fmaxf(sc[2][r], sc[3][r]));
#pragma unroll
      for (int off = 8; off >= 1; off >>= 1) v = fmaxf(v, __shfl_xor(v, off));
      const float mn = fmaxf(m_run[r], v);
      corr[r] = __expf(m_run[r] - mn);
      m_run[r] = mn;
      psum[r] = 0.f;
    }
#pragma unroll
    for (int c = 0; c < 4; ++c) {
#pragma unroll
      for (int r = 0; r < 4; ++r) {
        const float pv = __expf(sc[c][r] - m_run[r]);
        psum[r] += pv;
        pl[w][4 * lg + r][16 * c + l15] = __float2bfloat16(pv);
      }
    }
#pragma unroll
    for (int r = 0; r < 4; ++r) {
      float ps = psum[r];
#pragma unroll
      for (int off = 8; off >= 1; off >>= 1) ps += __shfl_xor(ps, off);
      l_run[r] = l_run[r] * corr[r] + ps;
    }
#pragma unroll
    for (int dt = 0; dt < 4; ++dt) {
      f32x4 o = acc_o[dt];
      o[0] *= corr[0]; o[1] *= corr[1]; o[2] *= corr[2]; o[3] *= corr[3];
      acc_o[dt] = o;
    }

    // PV: O += P[16q x 64t] * V[64t x 64d]; P via per-wave LDS (layout fix)
#pragma unroll
    for (int ks2 = 0; ks2 < 2; ++ks2) {
      const bf16x8 pa = *(const bf16x8*)&pl[w][l15][32 * ks2 + 8 * lg];
#pragma unroll
      for (int dt = 0; dt < 4; ++dt) {
        const bf16x8 vb = *(const bf16x8*)&vts[16 * dt + l15][32 * ks2 + 8 * lg];
        acc_o[dt] = __builtin_amdgcn_mfma_f32_16x16x32_bf16(pa, vb, acc_o[dt], 0, 0, 0);
      }
    }
    __syncthreads();
  }

  // write partials (unnormalized O + per-query m,l)
  float* Op = Opart + (((size_t)s * NH + h) * NT) * HD;
#pragma unroll
  for (int dt = 0; dt < 4; ++dt) {
#pragma unroll
    for (int r = 0; r < 4; ++r)
      Op[(size_t)(q0 + 4 * lg + r) * HD + 16 * dt + l15] = acc_o[dt][r];
  }
  if (l15 == 0) {
#pragma unroll
    for (int r = 0; r < 4; ++r)
      mlpart[((size_t)s * NH + h) * NT + q0 + 4 * lg + r] =
          make_float2(m_run[r], l_run[r]);
  }
}

// Combine the 4 stripes: O = sum_s Opart_s*exp(m_s-M) / sum_s l_s*exp(m_s-M)
__global__ __launch_bounds__(256) void attn_merge(
    const float* __restrict__ Opart, const float2* __restrict__ mlpart,
    float* __restrict__ Ow) {
  const int idx = blockIdx.x * 256 + threadIdx.x;
  if (idx >= NH * NT * HD) return;
  const int d = idx & 63;
  const int hn = idx >> 6;
  const int n = hn % NT;
  const int h = hn / NT;
  float m[4], lv[4];
  float M = -1e30f;
#pragma unroll
  for (int s = 0; s < 4; ++s) {
    const float2 ml = mlpart[((size_t)s * NH + h) * NT + n];
    m[s] = ml.x; lv[s] = ml.y;
    M = fmaxf(M, m[s]);
  }
  float L = 0.f, O = 0.f;
#pragma unroll
  for (int s = 0; s < 4; ++s) {
    const float e = __expf(m[s] - M);
    L += lv[s] * e;
    O += Opart[(((size_t)s * NH + h) * NT + n) * HD + d] * e;
  }
  Ow[(size_t)n * CC + h * HD + d] = O / L;
}

// ---------------------------------------------------------------------------
extern "C" void kernel_launch(void* const* d_in, const int* in_sizes, int n_in,
                              void* d_out, int out_size, void* d_ws,
                              size_t ws_size, hipStream_t stream) {
  const float* x       = (const float*)d_in[0];
  const float* qkv_w   = (const float*)d_in[1];
  const float* qkv_b   = (const float*)d_in[2];
  const float* proj_w  = (const float*)d_in[3];
  const float* proj_b  = (const float*)d_in[4];
  const float* k_cache = (const float*)d_in[5];
  const float* v_cache = (const float*)d_in[6];
  const float* k_specl = (const float*)d_in[7];
  const float* v_specl = (const float*)d_in[8];
  float* out = (float*)d_out;

  // workspace layout (~50.4 MiB)
  char* ws = (char*)d_ws;
  const size_t qb_bytes = (size_t)NH * NT * HD * 2;        //   884,736
  const size_t kv_bytes = (size_t)NH * MP * HD * 2;        // 21,430,272
  const size_t op_bytes = (size_t)4 * NH * NT * HD * 4;    //  7,077,888
  const size_t ml_bytes = (size_t)4 * NH * NT * 8;         //    221,184
  __hip_bfloat16* Qb = (__hip_bfloat16*)ws;
  __hip_bfloat16* Kf = (__hip_bfloat16*)(ws + qb_bytes);
  __hip_bfloat16* Vt = (__hip_bfloat16*)(ws + qb_bytes + kv_bytes);
  float* Opart = (float*)(ws + qb_bytes + 2 * kv_bytes);
  float2* mlpart = (float2*)(ws + qb_bytes + 2 * kv_bytes + op_bytes);
  float* Ow = (float*)(ws + qb_bytes + 2 * kv_bytes + op_bytes + ml_bytes);

  // 1) QKV projection (576 x 2304 x 768), scatter to Qb/Kf/Vt
  gemm_kernel<0><<<dim3(36, 18), 256, 0, stream>>>(x, qkv_w, qkv_b, nullptr,
                                                   Qb, Kf, Vt);
  // 2) gather cache/special into Kf and transposed Vt
  {
    const int totk = NH * NEW0 * 16;
    gather_k<<<dim3((totk + 255) / 256), 256, 0, stream>>>(k_cache, k_specl, Kf);
    gather_vt<<<dim3((NEW0 + 255) / 256, NH), 256, 0, stream>>>(v_cache, v_specl, Vt);
  }
  // 3) MFMA flash attention partials + merge
  attn_partial<<<dim3(432), 256, 0, stream>>>(Qb, Kf, Vt, Opart, mlpart);
  attn_merge<<<dim3((NH * NT * HD + 255) / 256), 256, 0, stream>>>(Opart, mlpart, Ow);
  // 4) output projection (576 x 768 x 768)
  gemm_kernel<1><<<dim3(12, 18), 256, 0, stream>>>(Ow, proj_w, proj_b, out,
                                                   nullptr, nullptr, nullptr);
}